// Round 1
// baseline (5930.870 us; speedup 1.0000x reference)
//
#include <hip/hip_runtime.h>

#define HID 512
#define TSTEPS 1024

typedef short bf16x8 __attribute__((ext_vector_type(8)));
typedef float fx4 __attribute__((ext_vector_type(4)));
typedef unsigned ux2 __attribute__((ext_vector_type(2)));

__device__ __forceinline__ short f2bf(float f) {
  unsigned u = __builtin_bit_cast(unsigned, f);
  u = (u + 0x7fffu + ((u >> 16) & 1u)) >> 16;   // RNE
  return (short)u;
}

// ---------------- Kernel A: vin = x @ W_in + b_in  (written into d_out) ----------------
// M = B*T = 65536, K = 256, N = 512. Tile 128x128, BK=32, 4 waves (2x2), bf16 MFMA.
__global__ __launch_bounds__(256) void vin_gemm(
    const float* __restrict__ x, const float* __restrict__ W_in,
    const float* __restrict__ b_in, float* __restrict__ out)
{
  __shared__ __align__(16) char smA[128 * 32 * 2];   // bf16 [row][k], XOR-swizzled
  __shared__ __align__(16) char smB[128 * 32 * 2];   // bf16 [col][k], XOR-swizzled
  const int tid = threadIdx.x;
  const int wave = tid >> 6, lane = tid & 63;
  const int lg = lane >> 4, lr = lane & 15;
  const int wm = wave >> 1, wn = wave & 1;
  const int r0 = blockIdx.x * 128, c0 = blockIdx.y * 128;

  fx4 acc[4][4] = {};

  const int arow = tid >> 3, aseg = tid & 7;   // A: 4 rows (arow + q*32), 4 f32 each
  const int bk = tid >> 3, bq = tid & 7;       // B: k-row bk, 4 cols per q-chunk

  for (int k0 = 0; k0 < 256; k0 += 32) {
    // stage A (x tile) -> bf16, swizzled
    #pragma unroll
    for (int q = 0; q < 4; ++q) {
      int row = arow + q * 32;
      fx4 fv = *(const fx4*)(x + (size_t)(r0 + row) * 256 + k0 + aseg * 4);
      ux2 p;
      p[0] = (unsigned)(unsigned short)f2bf(fv[0]) | ((unsigned)(unsigned short)f2bf(fv[1]) << 16);
      p[1] = (unsigned)(unsigned short)f2bf(fv[2]) | ((unsigned)(unsigned short)f2bf(fv[3]) << 16);
      int addr = (row * 64 + aseg * 8) ^ ((row & 7) << 4);
      *(ux2*)(smA + addr) = p;
    }
    // stage B (W_in tile), transposed to [col][k]
    #pragma unroll
    for (int q = 0; q < 4; ++q) {
      fx4 fv = *(const fx4*)(W_in + (size_t)(k0 + bk) * HID + c0 + q * 32 + bq * 4);
      #pragma unroll
      for (int e = 0; e < 4; ++e) {
        int col = q * 32 + bq * 4 + e;
        int addr = (col * 64 + bk * 2) ^ ((col & 7) << 4);
        *(short*)(smB + addr) = f2bf(fv[e]);
      }
    }
    __syncthreads();
    bf16x8 af[4];
    #pragma unroll
    for (int mt = 0; mt < 4; ++mt) {
      int row = wm * 64 + mt * 16 + lr;
      af[mt] = *(const bf16x8*)(smA + ((row * 64 + lg * 16) ^ ((row & 7) << 4)));
    }
    #pragma unroll
    for (int nt = 0; nt < 4; ++nt) {
      int col = wn * 64 + nt * 16 + lr;
      bf16x8 bf = *(const bf16x8*)(smB + ((col * 64 + lg * 16) ^ ((col & 7) << 4)));
      #pragma unroll
      for (int mt = 0; mt < 4; ++mt)
        acc[mt][nt] = __builtin_amdgcn_mfma_f32_16x16x32_bf16(af[mt], bf, acc[mt][nt], 0, 0, 0);
    }
    __syncthreads();
  }
  float bi[4];
  #pragma unroll
  for (int nt = 0; nt < 4; ++nt) bi[nt] = b_in[c0 + wn * 64 + nt * 16 + lr];
  #pragma unroll
  for (int mt = 0; mt < 4; ++mt)
    #pragma unroll
    for (int nt = 0; nt < 4; ++nt)
      #pragma unroll
      for (int jj = 0; jj < 4; ++jj) {
        int grow = r0 + wm * 64 + mt * 16 + lg * 4 + jj;
        int gcol = c0 + wn * 64 + nt * 16 + lr;
        out[(size_t)grow * HID + gcol] = acc[mt][nt][jj] + bi[nt];
      }
}

// ---------------- Kernel B: persistent recurrent scan ----------------
// 4 WGs x 16 batches. 8 waves/WG, wave owns 64 output cols (4 n-tiles:
// tiles 0..2 weights in VGPR bf16, tile 3 in LDS). fr double-buffered in LDS.
// LDS map: [0,128K) W_lds [col 0..127][k 0..511] bf16 swz; [128K,144K) frbuf0; [144K,160K) frbuf1.
#define FR0_OFF (128 * 1024)

__global__ __launch_bounds__(512, 2) void rnn_scan(
    float* base,                                  // d_out: vin in, fr out (aliases!)
    const float* __restrict__ init_state,
    const float* __restrict__ W_hid,
    const float* __restrict__ b_hid,
    const float* __restrict__ alpha)
{
  extern __shared__ __align__(16) char smem[];
  const int tid = threadIdx.x;
  const int wave = tid >> 6, lane = tid & 63;
  const int lg = lane >> 4, lr = lane & 15;
  const int bwg = blockIdx.x;
  const int cb = wave * 64;

  // ---- load weights (bf16): tiles 0..2 -> regs, tile 3 -> LDS ----
  bf16x8 wreg[3][16];
  #pragma unroll
  for (int nt = 0; nt < 4; ++nt) {
    const int col = cb + nt * 16 + lr;
    #pragma unroll
    for (int kk = 0; kk < 16; ++kk) {
      const int k0 = kk * 32 + lg * 8;
      bf16x8 w;
      #pragma unroll
      for (int j = 0; j < 8; ++j)
        w[j] = f2bf(W_hid[(size_t)(k0 + j) * HID + col]);
      if (nt < 3) {
        wreg[nt][kk] = w;
      } else {
        const int cw = wave * 16 + lr;
        int addr = (cw * 1024 + kk * 64 + lg * 16) ^ ((cw & 7) << 4);
        *(bf16x8*)(smem + addr) = w;
      }
    }
  }

  float al[4], bh[4], v[4][4];
  #pragma unroll
  for (int nt = 0; nt < 4; ++nt) {
    al[nt] = alpha[cb + nt * 16 + lr];
    bh[nt] = b_hid[cb + nt * 16 + lr];
  }
  #pragma unroll
  for (int nt = 0; nt < 4; ++nt)
    #pragma unroll
    for (int jj = 0; jj < 4; ++jj)
      v[nt][jj] = init_state[(size_t)(bwg * 16 + lg * 4 + jj) * HID + cb + nt * 16 + lr];

  // fr0 = relu(v0) into buffer 0
  #pragma unroll
  for (int nt = 0; nt < 4; ++nt)
    #pragma unroll
    for (int jj = 0; jj < 4; ++jj) {
      int row = lg * 4 + jj;
      int addr = (FR0_OFF + row * 1024 + (cb + nt * 16 + lr) * 2) ^ ((row & 7) << 4);
      *(short*)(smem + addr) = f2bf(fmaxf(v[nt][jj], 0.f));
    }
  __syncthreads();

  int off[4];
  #pragma unroll
  for (int jj = 0; jj < 4; ++jj)
    off[jj] = (lg * 4 + jj) * TSTEPS * HID + cb + lr;
  float* bb = base + (size_t)bwg * 16 * TSTEPS * HID;

  const int aswz = (lr & 7) << 4;
  const int abase0 = lr * 1024 + lg * 16;
  const int cw = wave * 16 + lr;
  const int wbase = cw * 1024 + lg * 16;
  const int wswz = (cw & 7) << 4;

  for (int t = 0; t < TSTEPS; ++t) {
    const int rb = FR0_OFF + ((t & 1) << 14);
    const int wb = FR0_OFF + (((t + 1) & 1) << 14);
    float vin[4][4];
    fx4 acc[4] = {};

    // first-half vin loads (issued early; latency hides under MFMA/DS chain)
    #pragma unroll
    for (int nt = 0; nt < 2; ++nt)
      #pragma unroll
      for (int jj = 0; jj < 4; ++jj)
        vin[nt][jj] = bb[t * HID + off[jj] + nt * 16];

    #pragma unroll
    for (int kk = 0; kk < 16; ++kk) {
      if (kk == 8) {
        #pragma unroll
        for (int nt = 2; nt < 4; ++nt)
          #pragma unroll
          for (int jj = 0; jj < 4; ++jj)
            vin[nt][jj] = bb[t * HID + off[jj] + nt * 16];
      }
      bf16x8 a  = *(const bf16x8*)(smem + ((rb + abase0 + kk * 64) ^ aswz));
      bf16x8 b3 = *(const bf16x8*)(smem + ((wbase + kk * 64) ^ wswz));
      acc[0] = __builtin_amdgcn_mfma_f32_16x16x32_bf16(a, wreg[0][kk], acc[0], 0, 0, 0);
      acc[1] = __builtin_amdgcn_mfma_f32_16x16x32_bf16(a, wreg[1][kk], acc[1], 0, 0, 0);
      acc[2] = __builtin_amdgcn_mfma_f32_16x16x32_bf16(a, wreg[2][kk], acc[2], 0, 0, 0);
      acc[3] = __builtin_amdgcn_mfma_f32_16x16x32_bf16(a, b3,          acc[3], 0, 0, 0);
    }

    // v update + relu + global store + bf16 fr into write buffer
    #pragma unroll
    for (int nt = 0; nt < 4; ++nt)
      #pragma unroll
      for (int jj = 0; jj < 4; ++jj) {
        float s  = acc[nt][jj] + bh[nt] + vin[nt][jj];
        float nv = v[nt][jj] + al[nt] * (s - v[nt][jj]);
        v[nt][jj] = nv;
        float fr = fmaxf(nv, 0.f);
        bb[t * HID + off[jj] + nt * 16] = fr;
        int row = lg * 4 + jj;
        int addr = (wb + row * 1024 + (cb + nt * 16 + lr) * 2) ^ ((row & 7) << 4);
        *(short*)(smem + addr) = f2bf(fr);
      }
    __syncthreads();   // one barrier/step: write-buffer visible, read-buffer free
  }
}

extern "C" void kernel_launch(void* const* d_in, const int* in_sizes, int n_in,
                              void* d_out, int out_size, void* d_ws, size_t ws_size,
                              hipStream_t stream) {
  const float* x     = (const float*)d_in[0];
  const float* inist = (const float*)d_in[1];
  const float* W_in  = (const float*)d_in[2];
  const float* b_in  = (const float*)d_in[3];
  const float* W_hid = (const float*)d_in[4];
  const float* b_hid = (const float*)d_in[5];
  const float* alph  = (const float*)d_in[6];
  float* out = (float*)d_out;
  (void)in_sizes; (void)n_in; (void)out_size; (void)d_ws; (void)ws_size;

  // Stage 1: vin for all timesteps into d_out (overwritten in place by stage 2).
  vin_gemm<<<dim3(512, 4), dim3(256), 0, stream>>>(x, W_in, b_in, out);

  // Stage 2: persistent scan, 160 KB dynamic LDS.
  (void)hipFuncSetAttribute(reinterpret_cast<const void*>(rnn_scan),
                            hipFuncAttributeMaxDynamicSharedMemorySize, 160 * 1024);
  rnn_scan<<<dim3(4), dim3(512), 160 * 1024, stream>>>(out, inist, W_hid, b_hid, alph);
}

// Round 3
// 4939.600 us; speedup vs baseline: 1.2007x; 1.2007x over previous
//
#include <hip/hip_runtime.h>

#define HID 512
#define TSTEPS 1024

typedef short bf16x8 __attribute__((ext_vector_type(8)));
typedef float fx4 __attribute__((ext_vector_type(4)));
typedef unsigned ux2 __attribute__((ext_vector_type(2)));

__device__ __forceinline__ short f2bf(float f) {
  unsigned u = __builtin_bit_cast(unsigned, f);
  u = (u + 0x7fffu + ((u >> 16) & 1u)) >> 16;   // RNE
  return (short)u;
}

// ---------------- Kernel A: vin = x @ W_in + b_in + b_hid  (into d_out) ----------------
// M = B*T = 65536, K = 256, N = 512. Tile 128x128, BK=32, 4 waves (2x2), bf16 MFMA.
// b_hid is folded in here so the scan kernel's accumulator init is just the vin load.
__global__ __launch_bounds__(256) void vin_gemm(
    const float* __restrict__ x, const float* __restrict__ W_in,
    const float* __restrict__ b_in, const float* __restrict__ b_hid,
    float* __restrict__ out)
{
  __shared__ __align__(16) char smA[128 * 32 * 2];   // bf16 [row][k], XOR-swizzled
  __shared__ __align__(16) char smB[128 * 32 * 2];   // bf16 [col][k], XOR-swizzled
  const int tid = threadIdx.x;
  const int wave = tid >> 6, lane = tid & 63;
  const int lg = lane >> 4, lr = lane & 15;
  const int wm = wave >> 1, wn = wave & 1;
  const int r0 = blockIdx.x * 128, c0 = blockIdx.y * 128;

  fx4 acc[4][4] = {};

  const int arow = tid >> 3, aseg = tid & 7;   // A: 4 rows (arow + q*32), 4 f32 each
  const int bk = tid >> 3, bq = tid & 7;       // B: k-row bk, 4 cols per q-chunk

  for (int k0 = 0; k0 < 256; k0 += 32) {
    // stage A (x tile) -> bf16, swizzled
    #pragma unroll
    for (int q = 0; q < 4; ++q) {
      int row = arow + q * 32;
      fx4 fv = *(const fx4*)(x + (size_t)(r0 + row) * 256 + k0 + aseg * 4);
      ux2 p;
      p[0] = (unsigned)(unsigned short)f2bf(fv[0]) | ((unsigned)(unsigned short)f2bf(fv[1]) << 16);
      p[1] = (unsigned)(unsigned short)f2bf(fv[2]) | ((unsigned)(unsigned short)f2bf(fv[3]) << 16);
      int addr = (row * 64 + aseg * 8) ^ ((row & 7) << 4);
      *(ux2*)(smA + addr) = p;
    }
    // stage B (W_in tile), transposed to [col][k]
    #pragma unroll
    for (int q = 0; q < 4; ++q) {
      fx4 fv = *(const fx4*)(W_in + (size_t)(k0 + bk) * HID + c0 + q * 32 + bq * 4);
      #pragma unroll
      for (int e = 0; e < 4; ++e) {
        int col = q * 32 + bq * 4 + e;
        int addr = (col * 64 + bk * 2) ^ ((col & 7) << 4);
        *(short*)(smB + addr) = f2bf(fv[e]);
      }
    }
    __syncthreads();
    bf16x8 af[4];
    #pragma unroll
    for (int mt = 0; mt < 4; ++mt) {
      int row = wm * 64 + mt * 16 + lr;
      af[mt] = *(const bf16x8*)(smA + ((row * 64 + lg * 16) ^ ((row & 7) << 4)));
    }
    #pragma unroll
    for (int nt = 0; nt < 4; ++nt) {
      int col = wn * 64 + nt * 16 + lr;
      bf16x8 bf = *(const bf16x8*)(smB + ((col * 64 + lg * 16) ^ ((col & 7) << 4)));
      #pragma unroll
      for (int mt = 0; mt < 4; ++mt)
        acc[mt][nt] = __builtin_amdgcn_mfma_f32_16x16x32_bf16(af[mt], bf, acc[mt][nt], 0, 0, 0);
    }
    __syncthreads();
  }
  float bi[4];
  #pragma unroll
  for (int nt = 0; nt < 4; ++nt) {
    int c = c0 + wn * 64 + nt * 16 + lr;
    bi[nt] = b_in[c] + b_hid[c];
  }
  #pragma unroll
  for (int mt = 0; mt < 4; ++mt)
    #pragma unroll
    for (int nt = 0; nt < 4; ++nt)
      #pragma unroll
      for (int jj = 0; jj < 4; ++jj) {
        int grow = r0 + wm * 64 + mt * 16 + lg * 4 + jj;
        int gcol = c0 + wn * 64 + nt * 16 + lr;
        out[(size_t)grow * HID + gcol] = acc[mt][nt][jj] + bi[nt];
      }
}

// ---------------- Kernel B: persistent recurrent scan ----------------
// 4 WGs x 16 batches. 8 waves/WG, wave owns 64 output cols (4 n-tiles:
// tiles 0..2 weights in VGPR bf16 (192 regs), tile 3 in LDS). fr double-buffered.
// LDS map: [0,128K) W_lds [wave*16+lr][k] bf16 swz; [128K,144K) frbuf0; [144K,160K) frbuf1.
// Register budget (2 waves/SIMD -> 256 cap): wreg 192 + acc 16 + v 16 + al 4 + addr ~14 = ~245.
#define FR0_OFF (128 * 1024)

__global__ __launch_bounds__(512, 2) void rnn_scan(
    float* base,                                  // d_out: vin in, fr out (aliases!)
    const float* __restrict__ init_state,
    const float* __restrict__ W_hid,
    const float* __restrict__ alpha)
{
  extern __shared__ __align__(16) char smem[];
  const int tid = threadIdx.x;
  const int wave = tid >> 6, lane = tid & 63;
  const int lg = lane >> 4, lr = lane & 15;
  const int bwg = blockIdx.x;
  const int cb = wave * 64;

  // ---- load weights (bf16): n-tiles 0..2 -> regs, tile 3 -> LDS ----
  bf16x8 wreg[3][16];
  #pragma unroll
  for (int nt = 0; nt < 4; ++nt) {
    const int col = cb + nt * 16 + lr;
    #pragma unroll
    for (int kk = 0; kk < 16; ++kk) {
      const int k0 = kk * 32 + lg * 8;
      bf16x8 w;
      #pragma unroll
      for (int j = 0; j < 8; ++j)
        w[j] = f2bf(W_hid[(size_t)(k0 + j) * HID + col]);
      if (nt < 3) {
        wreg[nt][kk] = w;
      } else {
        const int cw = wave * 16 + lr;
        int addr = (cw * 1024 + kk * 64 + lg * 16) ^ ((cw & 7) << 4);
        *(bf16x8*)(smem + addr) = w;
      }
    }
  }

  float al[4], v[4][4];
  #pragma unroll
  for (int nt = 0; nt < 4; ++nt) al[nt] = alpha[cb + nt * 16 + lr];
  #pragma unroll
  for (int nt = 0; nt < 4; ++nt)
    #pragma unroll
    for (int jj = 0; jj < 4; ++jj)
      v[nt][jj] = init_state[(size_t)(bwg * 16 + lg * 4 + jj) * HID + cb + nt * 16 + lr];

  // fr0 = relu(v0) into buffer 0
  #pragma unroll
  for (int nt = 0; nt < 4; ++nt)
    #pragma unroll
    for (int jj = 0; jj < 4; ++jj) {
      int row = lg * 4 + jj;
      int addr = (FR0_OFF + row * 1024 + (cb + nt * 16 + lr) * 2) ^ ((row & 7) << 4);
      *(short*)(smem + addr) = f2bf(fmaxf(v[nt][jj], 0.f));
    }

  int off[4];
  #pragma unroll
  for (int jj = 0; jj < 4; ++jj)
    off[jj] = (lg * 4 + jj) * TSTEPS * HID + cb + lr;
  float* bb = base + (size_t)bwg * 16 * TSTEPS * HID;

  // pipeline prologue: vin loads for t=0 (includes b_in + b_hid from vin_gemm)
  float vld[4][4];
  #pragma unroll
  for (int nt = 0; nt < 4; ++nt)
    #pragma unroll
    for (int jj = 0; jj < 4; ++jj)
      vld[nt][jj] = bb[off[jj] + nt * 16];

  __syncthreads();

  const int aswz = (lr & 7) << 4;
  const int abase0 = lr * 1024 + lg * 16;
  const int cw = wave * 16 + lr;
  const int wbase = cw * 1024 + lg * 16;
  const int wswz = (cw & 7) << 4;

  for (int t = 0; t < TSTEPS; ++t) {
    const int rb = FR0_OFF + ((t & 1) << 14);
    const int wb = FR0_OFF + (((t + 1) & 1) << 14);

    // accumulator init = vin (+biases, prefolded) — consumes the pipelined loads
    fx4 acc[4];
    #pragma unroll
    for (int nt = 0; nt < 4; ++nt)
      #pragma unroll
      for (int jj = 0; jj < 4; ++jj)
        acc[nt][jj] = vld[nt][jj];

    #pragma unroll
    for (int kk = 0; kk < 16; ++kk) {
      bf16x8 a  = *(const bf16x8*)(smem + ((rb + abase0 + kk * 64) ^ aswz));
      bf16x8 b3 = *(const bf16x8*)(smem + ((wbase + kk * 64) ^ wswz));
      acc[0] = __builtin_amdgcn_mfma_f32_16x16x32_bf16(a, wreg[0][kk], acc[0], 0, 0, 0);
      acc[1] = __builtin_amdgcn_mfma_f32_16x16x32_bf16(a, wreg[1][kk], acc[1], 0, 0, 0);
      acc[2] = __builtin_amdgcn_mfma_f32_16x16x32_bf16(a, wreg[2][kk], acc[2], 0, 0, 0);
      acc[3] = __builtin_amdgcn_mfma_f32_16x16x32_bf16(a, b3,          acc[3], 0, 0, 0);
    }

    // v update + relu + global store + bf16 fr into write buffer
    #pragma unroll
    for (int nt = 0; nt < 4; ++nt)
      #pragma unroll
      for (int jj = 0; jj < 4; ++jj) {
        float nv = v[nt][jj] + al[nt] * (acc[nt][jj] - v[nt][jj]);
        v[nt][jj] = nv;
        float fr = fmaxf(nv, 0.f);
        bb[t * HID + off[jj] + nt * 16] = fr;
        int row = lg * 4 + jj;
        int addr = (wb + row * 1024 + (cb + nt * 16 + lr) * 2) ^ ((row & 7) << 4);
        *(short*)(smem + addr) = f2bf(fr);
      }

    // issue next step's vin loads before the barrier (latency hides across it)
    if (t + 1 < TSTEPS) {
      #pragma unroll
      for (int nt = 0; nt < 4; ++nt)
        #pragma unroll
        for (int jj = 0; jj < 4; ++jj)
          vld[nt][jj] = bb[(t + 1) * HID + off[jj] + nt * 16];
    }

    __syncthreads();   // one barrier/step: write-buffer visible, read-buffer free
  }
}

extern "C" void kernel_launch(void* const* d_in, const int* in_sizes, int n_in,
                              void* d_out, int out_size, void* d_ws, size_t ws_size,
                              hipStream_t stream) {
  const float* x     = (const float*)d_in[0];
  const float* inist = (const float*)d_in[1];
  const float* W_in  = (const float*)d_in[2];
  const float* b_in  = (const float*)d_in[3];
  const float* W_hid = (const float*)d_in[4];
  const float* b_hid = (const float*)d_in[5];
  const float* alph  = (const float*)d_in[6];
  float* out = (float*)d_out;
  (void)in_sizes; (void)n_in; (void)out_size; (void)d_ws; (void)ws_size;

  // Stage 1: vin (+b_in +b_hid) for all timesteps into d_out.
  vin_gemm<<<dim3(512, 4), dim3(256), 0, stream>>>(x, W_in, b_in, b_hid, out);

  // Stage 2: persistent scan, 160 KB dynamic LDS.
  (void)hipFuncSetAttribute(reinterpret_cast<const void*>(rnn_scan),
                            hipFuncAttributeMaxDynamicSharedMemorySize, 160 * 1024);
  rnn_scan<<<dim3(4), dim3(512), 160 * 1024, stream>>>(out, inist, W_hid, alph);
}

// Round 6
// 4078.290 us; speedup vs baseline: 1.4543x; 1.2112x over previous
//
#include <hip/hip_runtime.h>

#define HID 512
#define TSTEPS 1024

typedef short bf16x8 __attribute__((ext_vector_type(8)));
typedef float fx4 __attribute__((ext_vector_type(4)));
typedef unsigned ux2 __attribute__((ext_vector_type(2)));

__device__ __forceinline__ short f2bf(float f) {
  unsigned u = __builtin_bit_cast(unsigned, f);
  u = (u + 0x7fffu + ((u >> 16) & 1u)) >> 16;   // RNE
  return (short)u;
}

// ---------------- Kernel A: vin = x @ W_in + b_in + b_hid  (into d_out) ----------------
// M = B*T = 65536, K = 256, N = 512. Tile 128x128, BK=32, 4 waves (2x2), bf16 MFMA.
__global__ __launch_bounds__(256) void vin_gemm(
    const float* __restrict__ x, const float* __restrict__ W_in,
    const float* __restrict__ b_in, const float* __restrict__ b_hid,
    float* __restrict__ out)
{
  __shared__ __align__(16) char smA[128 * 32 * 2];   // bf16 [row][k], XOR-swizzled
  __shared__ __align__(16) char smB[128 * 32 * 2];   // bf16 [col][k], XOR-swizzled
  const int tid = threadIdx.x;
  const int wave = tid >> 6, lane = tid & 63;
  const int lg = lane >> 4, lr = lane & 15;
  const int wm = wave >> 1, wn = wave & 1;
  const int r0 = blockIdx.x * 128, c0 = blockIdx.y * 128;

  fx4 acc[4][4] = {};

  const int arow = tid >> 3, aseg = tid & 7;
  const int bk = tid >> 3, bq = tid & 7;

  for (int k0 = 0; k0 < 256; k0 += 32) {
    #pragma unroll
    for (int q = 0; q < 4; ++q) {
      int row = arow + q * 32;
      fx4 fv = *(const fx4*)(x + (size_t)(r0 + row) * 256 + k0 + aseg * 4);
      ux2 p;
      p[0] = (unsigned)(unsigned short)f2bf(fv[0]) | ((unsigned)(unsigned short)f2bf(fv[1]) << 16);
      p[1] = (unsigned)(unsigned short)f2bf(fv[2]) | ((unsigned)(unsigned short)f2bf(fv[3]) << 16);
      int addr = (row * 64 + aseg * 8) ^ ((row & 7) << 4);
      *(ux2*)(smA + addr) = p;
    }
    #pragma unroll
    for (int q = 0; q < 4; ++q) {
      fx4 fv = *(const fx4*)(W_in + (size_t)(k0 + bk) * HID + c0 + q * 32 + bq * 4);
      #pragma unroll
      for (int e = 0; e < 4; ++e) {
        int col = q * 32 + bq * 4 + e;
        int addr = (col * 64 + bk * 2) ^ ((col & 7) << 4);
        *(short*)(smB + addr) = f2bf(fv[e]);
      }
    }
    __syncthreads();
    bf16x8 af[4];
    #pragma unroll
    for (int mt = 0; mt < 4; ++mt) {
      int row = wm * 64 + mt * 16 + lr;
      af[mt] = *(const bf16x8*)(smA + ((row * 64 + lg * 16) ^ ((row & 7) << 4)));
    }
    #pragma unroll
    for (int nt = 0; nt < 4; ++nt) {
      int col = wn * 64 + nt * 16 + lr;
      bf16x8 bf = *(const bf16x8*)(smB + ((col * 64 + lg * 16) ^ ((col & 7) << 4)));
      #pragma unroll
      for (int mt = 0; mt < 4; ++mt)
        acc[mt][nt] = __builtin_amdgcn_mfma_f32_16x16x32_bf16(af[mt], bf, acc[mt][nt], 0, 0, 0);
    }
    __syncthreads();
  }
  float bi[4];
  #pragma unroll
  for (int nt = 0; nt < 4; ++nt) {
    int c = c0 + wn * 64 + nt * 16 + lr;
    bi[nt] = b_in[c] + b_hid[c];
  }
  #pragma unroll
  for (int mt = 0; mt < 4; ++mt)
    #pragma unroll
    for (int nt = 0; nt < 4; ++nt)
      #pragma unroll
      for (int jj = 0; jj < 4; ++jj) {
        int grow = r0 + wm * 64 + mt * 16 + lg * 4 + jj;
        int gcol = c0 + wn * 64 + nt * 16 + lr;
        out[(size_t)grow * HID + gcol] = acc[mt][nt][jj] + bi[nt];
      }
}

// ---------------- Kernel P: pack W_hid tile-2 fragments (bf16) into d_ws ----------------
// For wave w (cols w*64+32 .. w*64+47), kk 0..15, lane (lg,lr):
//   frag = W_hid[kk*32+lg*8 .. +8][w*64+32+lr] as bf16x8, stored contiguously:
//   ws[((w*16+kk)*64 + lane)*8 shorts]. Total 128 KB; read by all 4 WGs (L2-hit).
__global__ __launch_bounds__(512) void pack_w(const float* __restrict__ W_hid,
                                              short* __restrict__ ws)
{
  const int tid = threadIdx.x;
  const int wave = tid >> 6, lane = tid & 63;
  const int lg = lane >> 4, lr = lane & 15;
  const int col = wave * 64 + 32 + lr;
  for (int kk = 0; kk < 16; ++kk) {
    bf16x8 w;
    #pragma unroll
    for (int j = 0; j < 8; ++j)
      w[j] = f2bf(W_hid[(size_t)(kk * 32 + lg * 8 + j) * HID + col]);
    *(bf16x8*)(ws + ((size_t)((wave * 16 + kk) * 64 + lane)) * 8) = w;
  }
}

// ---------------- Kernel B: persistent recurrent scan ----------------
// 4 WGs x 16 batches, 8 waves/WG, wave owns 64 cols (4 n-tiles of 16):
//   tiles 0,1 -> VGPR bf16 (128 regs); tile 2 -> streamed from d_ws (L2); tile 3 -> LDS.
// fr double-buffered in LDS, write swizzle ^(lg<<5) (conflict-free stores).
// LDS: [0,128K) tile3 W [wave*16+lr][k] swz(cw&7)<<4; [128K,144K) fr0; [144K,160K) fr1.
// Live regs ~216: wreg 128 + acc 16 + v 16 + wst window ~32 + misc ~24.
#define FR0_OFF (128 * 1024)

__global__ __launch_bounds__(512, 2) void rnn_scan(
    float* base,                                  // d_out: vin in, fr out (aliases!)
    const float* __restrict__ init_state,
    const float* __restrict__ W_hid,
    const float* __restrict__ alpha,
    const short* __restrict__ wsf)                // packed tile-2 fragments
{
  extern __shared__ __align__(16) char smem[];
  const int tid = threadIdx.x;
  const int wave = tid >> 6, lane = tid & 63;
  const int lg = lane >> 4, lr = lane & 15;
  const int bwg = blockIdx.x;
  const int cb = wave * 64;

  // ---- weights: n-tiles 0,1 -> regs; tile 3 -> LDS ----
  bf16x8 wreg[2][16];
  #pragma unroll
  for (int nt = 0; nt < 4; ++nt) {
    if (nt == 2) continue;                        // tile 2 streamed at runtime
    const int col = cb + nt * 16 + lr;
    #pragma unroll
    for (int kk = 0; kk < 16; ++kk) {
      const int k0 = kk * 32 + lg * 8;
      bf16x8 w;
      #pragma unroll
      for (int j = 0; j < 8; ++j)
        w[j] = f2bf(W_hid[(size_t)(k0 + j) * HID + col]);
      if (nt < 2) {
        wreg[nt][kk] = w;
      } else {
        const int cw = wave * 16 + lr;
        int addr = (cw * 1024 + kk * 64 + lg * 16) ^ ((cw & 7) << 4);
        *(bf16x8*)(smem + addr) = w;
      }
    }
  }

  float al[4], v[4][4];
  #pragma unroll
  for (int nt = 0; nt < 4; ++nt) al[nt] = alpha[cb + nt * 16 + lr];
  #pragma unroll
  for (int nt = 0; nt < 4; ++nt)
    #pragma unroll
    for (int jj = 0; jj < 4; ++jj)
      v[nt][jj] = init_state[(size_t)(bwg * 16 + lg * 4 + jj) * HID + cb + nt * 16 + lr];

  // fr0 = relu(v0) into buffer 0 (write swizzle ^(lg<<5))
  #pragma unroll
  for (int nt = 0; nt < 4; ++nt)
    #pragma unroll
    for (int jj = 0; jj < 4; ++jj) {
      int row = lg * 4 + jj;
      int addr = (FR0_OFF + row * 1024 + (cb + nt * 16 + lr) * 2) ^ (lg << 5);
      *(short*)(smem + addr) = f2bf(fmaxf(v[nt][jj], 0.f));
    }

  int off[4];
  #pragma unroll
  for (int jj = 0; jj < 4; ++jj)
    off[jj] = (lg * 4 + jj) * TSTEPS * HID + cb + lr;
  float* bb = base + (size_t)bwg * 16 * TSTEPS * HID;

  // t=0 vin straight into the accumulator (b_in+b_hid pre-folded by vin_gemm)
  fx4 acc[4];
  #pragma unroll
  for (int nt = 0; nt < 4; ++nt)
    #pragma unroll
    for (int jj = 0; jj < 4; ++jj)
      acc[nt][jj] = bb[off[jj] + nt * 16];

  // per-wave stream base: fragments for (wave, kk, lane)
  const bf16x8* wsp = (const bf16x8*)(wsf + ((size_t)(wave * 16) * 64 + lane) * 8);
  bf16x8 wst[16];
  wst[0] = wsp[0];   wst[1] = wsp[64];  wst[2] = wsp[128]; wst[3] = wsp[192];

  __syncthreads();

  const int aswz = (lr >> 2) << 5;
  const int abase0 = lr * 1024 + lg * 16;
  const int cw = wave * 16 + lr;
  const int wbase = cw * 1024 + lg * 16;
  const int wswz = (cw & 7) << 4;
  const int frwswz = lg << 5;

  for (int t = 0; t < TSTEPS; ++t) {
    const int rb = FR0_OFF + ((t & 1) << 14);
    const int wb = FR0_OFF + (((t + 1) & 1) << 14);

    #pragma unroll
    for (int kk = 0; kk < 16; ++kk) {
      // rolling stream window: 4 fragments issued 4..8 kk ahead of use
      if (kk == 0) {
        wst[4] = wsp[4 * 64];  wst[5] = wsp[5 * 64];
        wst[6] = wsp[6 * 64];  wst[7] = wsp[7 * 64];
      }
      if (kk == 4) {
        wst[8]  = wsp[8 * 64];  wst[9]  = wsp[9 * 64];
        wst[10] = wsp[10 * 64]; wst[11] = wsp[11 * 64];
      }
      if (kk == 8) {
        wst[12] = wsp[12 * 64]; wst[13] = wsp[13 * 64];
        wst[14] = wsp[14 * 64]; wst[15] = wsp[15 * 64];
      }
      bf16x8 a  = *(const bf16x8*)(smem + ((rb + abase0 + kk * 64) ^ aswz));
      bf16x8 b3 = *(const bf16x8*)(smem + ((wbase + kk * 64) ^ wswz));
      acc[0] = __builtin_amdgcn_mfma_f32_16x16x32_bf16(a, wreg[0][kk], acc[0], 0, 0, 0);
      acc[1] = __builtin_amdgcn_mfma_f32_16x16x32_bf16(a, wreg[1][kk], acc[1], 0, 0, 0);
      acc[2] = __builtin_amdgcn_mfma_f32_16x16x32_bf16(a, wst[kk],     acc[2], 0, 0, 0);
      acc[3] = __builtin_amdgcn_mfma_f32_16x16x32_bf16(a, b3,          acc[3], 0, 0, 0);
    }

    // v update + relu + global store + bf16 fr into write buffer
    #pragma unroll
    for (int nt = 0; nt < 4; ++nt)
      #pragma unroll
      for (int jj = 0; jj < 4; ++jj) {
        float nv = v[nt][jj] + al[nt] * (acc[nt][jj] - v[nt][jj]);
        v[nt][jj] = nv;
        float fr = fmaxf(nv, 0.f);
        bb[t * HID + off[jj] + nt * 16] = fr;
        int row = lg * 4 + jj;
        int addr = (wb + row * 1024 + (cb + nt * 16 + lr) * 2) ^ frwswz;
        *(short*)(smem + addr) = f2bf(fr);
      }

    // prefetch next step's vin straight into acc (drains at the barrier)
    if (t + 1 < TSTEPS) {
      #pragma unroll
      for (int nt = 0; nt < 4; ++nt)
        #pragma unroll
        for (int jj = 0; jj < 4; ++jj)
          acc[nt][jj] = bb[(t + 1) * HID + off[jj] + nt * 16];
    }
    // stream window 0..3 for next step (constant data; drains at barrier)
    wst[0] = wsp[0];   wst[1] = wsp[64];  wst[2] = wsp[128]; wst[3] = wsp[192];

    __syncthreads();
  }
}

extern "C" void kernel_launch(void* const* d_in, const int* in_sizes, int n_in,
                              void* d_out, int out_size, void* d_ws, size_t ws_size,
                              hipStream_t stream) {
  const float* x     = (const float*)d_in[0];
  const float* inist = (const float*)d_in[1];
  const float* W_in  = (const float*)d_in[2];
  const float* b_in  = (const float*)d_in[3];
  const float* W_hid = (const float*)d_in[4];
  const float* b_hid = (const float*)d_in[5];
  const float* alph  = (const float*)d_in[6];
  float* out = (float*)d_out;
  (void)in_sizes; (void)n_in; (void)out_size; (void)ws_size;

  // Pack tile-2 W fragments into workspace (128 KB), then vin, then the scan.
  pack_w<<<dim3(1), dim3(512), 0, stream>>>(W_hid, (short*)d_ws);
  vin_gemm<<<dim3(512, 4), dim3(256), 0, stream>>>(x, W_in, b_in, b_hid, out);

  (void)hipFuncSetAttribute(reinterpret_cast<const void*>(rnn_scan),
                            hipFuncAttributeMaxDynamicSharedMemorySize, 160 * 1024);
  rnn_scan<<<dim3(4), dim3(512), 160 * 1024, stream>>>(out, inist, W_hid, alph,
                                                       (const short*)d_ws);
}